// Round 2
// baseline (424.357 us; speedup 1.0000x reference)
//
#include <hip/hip_runtime.h>
#include <stdint.h>

#define TT 2048
#define HH 16

typedef _Float16 f16;
typedef __attribute__((ext_vector_type(8))) _Float16 f16x8;
typedef __attribute__((ext_vector_type(4))) float f32x4;
typedef unsigned short ushort_t;

// async global->LDS, 16B per lane; LDS dest = wave-uniform base + lane*16
__device__ __forceinline__ void gl_lds16(const void* g, void* l){
  __builtin_amdgcn_global_load_lds(
      (__attribute__((address_space(1))) void*)(void*)g,
      (__attribute__((address_space(3))) void*)l, 16, 0, 0);
}

// ---------------- convert x: f32 -> f16, 4 elements/thread ----------------
__global__ __launch_bounds__(256) void cvt_f2h_kernel(const float4* __restrict__ in,
                                                      uint2* __restrict__ out, int n4){
  int i = blockIdx.x * 256 + threadIdx.x;
  if (i >= n4) return;
  float4 v = in[i];
  union { f16 h[4]; uint2 u; } o;
  o.h[0] = (f16)v.x; o.h[1] = (f16)v.y; o.h[2] = (f16)v.z; o.h[3] = (f16)v.w;
  out[i] = o.u;
}

// ---------------- transpose+convert: f32 [R][C] -> f16 [C][R] ----------------
__global__ __launch_bounds__(256) void transpose_cvt_kernel(const float* __restrict__ in,
                                                            f16* __restrict__ out, int R, int C){
  __shared__ float tile[64][65];
  int c0 = blockIdx.x * 64, r0 = blockIdx.y * 64;
  int t = threadIdx.x;
  int row = t >> 2, cs = (t & 3) << 4;
  const float4* src = (const float4*)(in + (size_t)(r0 + row) * C + c0 + cs);
  float4 a = src[0], b = src[1], c = src[2], d = src[3];
  float* tr = &tile[row][cs];
  tr[0]=a.x; tr[1]=a.y; tr[2]=a.z;  tr[3]=a.w;
  tr[4]=b.x; tr[5]=b.y; tr[6]=b.z;  tr[7]=b.w;
  tr[8]=c.x; tr[9]=c.y; tr[10]=c.z; tr[11]=c.w;
  tr[12]=d.x;tr[13]=d.y;tr[14]=d.z; tr[15]=d.w;
  __syncthreads();
  f16 tmp[16];
  #pragma unroll
  for (int j = 0; j < 16; ++j) tmp[j] = (f16)tile[cs + j][row];
  f16* dst = out + (size_t)(c0 + row) * R + r0 + cs;
  *(uint4*)dst = *(uint4*)&tmp[0];
  *(uint4*)(dst + 8) = *(uint4*)&tmp[8];
}

// ---------------- GEMM: C[M][N] = A[M][K] @ Bt[N][K]^T, f16 in, f16/f32 out ----------------
__global__ __launch_bounds__(256) void gemm_f16_kernel(const f16* __restrict__ A,
                                                       const f16* __restrict__ Bt,
                                                       void* __restrict__ Cout,
                                                       int M, int N, int K, int out_f32){
  __shared__ __align__(16) f16 As[128 * 32];
  __shared__ __align__(16) f16 Bs[128 * 32];
  int t = threadIdx.x;
  int w = t >> 6, lane = t & 63;
  int wm = (w >> 1) * 64, wn = (w & 1) * 64;
  int lrow = lane & 15, quad = lane >> 4;
  int bm = blockIdx.y, bn = blockIdx.x;

  f32x4 acc[4][4];
  for (int i = 0; i < 4; ++i)
    for (int j = 0; j < 4; ++j)
      for (int r = 0; r < 4; ++r) acc[i][j][r] = 0.f;

  const int nk = K >> 5;
  for (int kt = 0; kt < nk; ++kt){
    int k0 = kt << 5;
    __syncthreads();
    #pragma unroll
    for (int i = 0; i < 2; ++i){
      int c = (w << 7) + (i << 6) + lane;
      gl_lds16(A  + (size_t)((bm << 7) + (c >> 2)) * K + k0 + ((c & 3) << 3),
               As + ((w << 7) + (i << 6)) * 8);
      gl_lds16(Bt + (size_t)((bn << 7) + (c >> 2)) * K + k0 + ((c & 3) << 3),
               Bs + ((w << 7) + (i << 6)) * 8);
    }
    __syncthreads();
    f16x8 af[4], bfr[4];
    #pragma unroll
    for (int mi = 0; mi < 4; ++mi)
      af[mi] = *(const f16x8*)(As + (wm + mi * 16 + lrow) * 32 + quad * 8);
    #pragma unroll
    for (int ni = 0; ni < 4; ++ni)
      bfr[ni] = *(const f16x8*)(Bs + (wn + ni * 16 + lrow) * 32 + quad * 8);
    #pragma unroll
    for (int mi = 0; mi < 4; ++mi)
      #pragma unroll
      for (int ni = 0; ni < 4; ++ni)
        acc[mi][ni] = __builtin_amdgcn_mfma_f32_16x16x32_f16(af[mi], bfr[ni], acc[mi][ni], 0, 0, 0);
  }

  #pragma unroll
  for (int mi = 0; mi < 4; ++mi)
    #pragma unroll
    for (int ni = 0; ni < 4; ++ni)
      #pragma unroll
      for (int r = 0; r < 4; ++r){
        int row = (bm << 7) + wm + mi * 16 + quad * 4 + r;
        int col = (bn << 7) + wn + ni * 16 + lrow;
        float val = acc[mi][ni][r];
        if (out_f32) ((float*)Cout)[(size_t)row * N + col] = val;
        else         ((f16*)Cout)[(size_t)row * N + col] = (f16)val;
      }
}

// ---------------- fused causal graph attention ----------------
// qkv packed [B*T][3072] f16 (q|k|v each [H][64] within row). One block = (b,h,64-query tile).
__global__ __launch_bounds__(256) void attn_kernel(const f16* __restrict__ qkv,
                                                   const float* __restrict__ gadj,
                                                   const int* __restrict__ etype,
                                                   const float* __restrict__ adj_bias,
                                                   const float* __restrict__ edge_table,
                                                   f16* __restrict__ attn_out){
  __shared__ __align__(16) f16 Ks[64 * 64];
  __shared__ __align__(16) f16 Vs[64 * 68];   // pitch 68: v-frag reads <=2-way conflicts
  __shared__ __align__(16) f16 Ps[4][16 * 64];
  __shared__ float edge_lds[32];

  int bx = blockIdx.x;
  int h  = bx & 15;
  int qt = 31 - ((bx >> 4) & 31);   // descending qt: long blocks start first
  int b  = bx >> 9;
  int t  = threadIdx.x;
  int w = t >> 6, lane = t & 63;
  int lrow = lane & 15, quad = lane >> 4;

  if (t < 17) edge_lds[t] = edge_table[t * HH + h];
  float adjb = adj_bias[h];

  int q0 = qt * 64 + w * 16;
  const size_t qrow = ((size_t)b * TT + q0 + lrow) * 3072 + h * 64;
  f16x8 qf0 = *(const f16x8*)(qkv + qrow + quad * 8);
  f16x8 qf1 = *(const f16x8*)(qkv + qrow + 32 + quad * 8);

  f32x4 o[4];
  for (int i = 0; i < 4; ++i)
    for (int r = 0; r < 4; ++r) o[i][r] = 0.f;
  float mrun[4] = {-1e30f, -1e30f, -1e30f, -1e30f};
  float lrun[4] = {0.f, 0.f, 0.f, 0.f};

  for (int kt2 = 0; kt2 <= qt; ++kt2){
    __syncthreads();
    // stage K via async global->LDS (contiguous [64 key][64 hd])
    #pragma unroll
    for (int i = 0; i < 2; ++i){
      int c = (w << 7) + (i << 6) + lane;
      gl_lds16(qkv + ((size_t)b * TT + kt2 * 64 + (c >> 3)) * 3072 + 1024 + h * 64 + ((c & 7) << 3),
               Ks + ((w << 7) + (i << 6)) * 8);
    }
    // stage V manually into padded Vs (pitch 68)
    #pragma unroll
    for (int i = 0; i < 2; ++i){
      int c = (i << 8) + t;
      int vrow = c >> 3, hd0 = (c & 7) << 3;
      uint4 v = *(const uint4*)(qkv + ((size_t)b * TT + kt2 * 64 + vrow) * 3072 + 2048 + h * 64 + hd0);
      f16* d = Vs + vrow * 68 + hd0;
      *(uint2*)d = make_uint2(v.x, v.y);
      *(uint2*)(d + 4) = make_uint2(v.z, v.w);
    }
    __syncthreads();

    // S = Q K^T (fp32 accum)
    f32x4 sf[4];
    #pragma unroll
    for (int nb = 0; nb < 4; ++nb){
      f32x4 s = {0.f, 0.f, 0.f, 0.f};
      f16x8 kf0 = *(const f16x8*)(Ks + (nb * 16 + lrow) * 64 + quad * 8);
      f16x8 kf1 = *(const f16x8*)(Ks + (nb * 16 + lrow) * 64 + 32 + quad * 8);
      s = __builtin_amdgcn_mfma_f32_16x16x32_f16(qf0, kf0, s, 0, 0, 0);
      s = __builtin_amdgcn_mfma_f32_16x16x32_f16(qf1, kf1, s, 0, 0, 0);
      sf[nb] = s;
    }

    // bias + causal mask (C-layout: row = quad*4+r, col = lrow)
    float sarr[4][4];
    int qgb = q0 + quad * 4;
    int kgb = kt2 * 64 + lrow;
    bool diag = (kt2 == qt);
    #pragma unroll
    for (int nb = 0; nb < 4; ++nb){
      int kg = kgb + nb * 16;
      size_t idx0 = ((size_t)b * TT + qgb) * TT + kg;
      #pragma unroll
      for (int r = 0; r < 4; ++r){
        size_t idx = idx0 + (size_t)r * TT;
        float v;
        if (diag && kg > qgb + r) v = -1e30f;
        else v = sf[nb][r] * 0.125f + adjb * gadj[idx] + edge_lds[etype[idx]];
        sarr[nb][r] = v;
      }
    }

    // online softmax, rows live across 16 lanes of one quad (16 lanes = 16 cols)
    float pv_[4][4];
    #pragma unroll
    for (int r = 0; r < 4; ++r){
      float mx = fmaxf(fmaxf(sarr[0][r], sarr[1][r]), fmaxf(sarr[2][r], sarr[3][r]));
      mx = fmaxf(mx, __shfl_xor(mx, 1));
      mx = fmaxf(mx, __shfl_xor(mx, 2));
      mx = fmaxf(mx, __shfl_xor(mx, 4));
      mx = fmaxf(mx, __shfl_xor(mx, 8));
      float mnew = fmaxf(mrun[r], mx);
      float alpha = exp2f((mrun[r] - mnew) * 1.44269504089f);
      mrun[r] = mnew;
      float rs = 0.f;
      #pragma unroll
      for (int nb = 0; nb < 4; ++nb){
        float p = exp2f((sarr[nb][r] - mnew) * 1.44269504089f);
        pv_[nb][r] = p; rs += p;
      }
      rs += __shfl_xor(rs, 1); rs += __shfl_xor(rs, 2);
      rs += __shfl_xor(rs, 4); rs += __shfl_xor(rs, 8);
      lrun[r] = lrun[r] * alpha + rs;
      #pragma unroll
      for (int nbh = 0; nbh < 4; ++nbh) o[nbh][r] *= alpha;
    }

    // P: C-layout -> LDS -> A-layout (per-wave private region, wave-internal wait)
    f16* Pw = &Ps[w][0];
    #pragma unroll
    for (int nb = 0; nb < 4; ++nb)
      #pragma unroll
      for (int r = 0; r < 4; ++r)
        Pw[(quad * 4 + r) * 64 + nb * 16 + lrow] = (f16)pv_[nb][r];
    __asm__ volatile("s_waitcnt lgkmcnt(0)" ::: "memory");

    // O += P V
    #pragma unroll
    for (int c = 0; c < 2; ++c){
      f16x8 pf = *(const f16x8*)(Pw + lrow * 64 + c * 32 + quad * 8);
      #pragma unroll
      for (int nbh = 0; nbh < 4; ++nbh){
        f16x8 vf;
        #pragma unroll
        for (int j = 0; j < 8; ++j) vf[j] = Vs[(c * 32 + quad * 8 + j) * 68 + nbh * 16 + lrow];
        o[nbh] = __builtin_amdgcn_mfma_f32_16x16x32_f16(pf, vf, o[nbh], 0, 0, 0);
      }
    }
  }

  // epilogue: normalize + store f16 [B*T][1024]
  float inv[4];
  #pragma unroll
  for (int r = 0; r < 4; ++r) inv[r] = 1.0f / lrun[r];
  #pragma unroll
  for (int nbh = 0; nbh < 4; ++nbh)
    #pragma unroll
    for (int r = 0; r < 4; ++r){
      int qg = q0 + quad * 4 + r;
      int col = h * 64 + nbh * 16 + lrow;
      attn_out[((size_t)b * TT + qg) * 1024 + col] = (f16)(o[nbh][r] * inv[r]);
    }
}

extern "C" void kernel_launch(void* const* d_in, const int* in_sizes, int n_in,
                              void* d_out, int out_size, void* d_ws, size_t ws_size,
                              hipStream_t stream){
  (void)in_sizes; (void)n_in; (void)out_size; (void)ws_size;
  const float* x_f32  = (const float*)d_in[0];   // x f32 (B,T,D)
  const float* gadj   = (const float*)d_in[1];   // graph_adj f32 (B,T,T)
  const int*   etype  = (const int*)d_in[2];     // edge_types int32 (B,T,T)
  const float* wqkv   = (const float*)d_in[3];   // (D, 3D) f32
  const float* wproj  = (const float*)d_in[4];   // (D, D) f32
  const float* adjb   = (const float*)d_in[5];   // (H,) f32
  const float* etab   = (const float*)d_in[6];   // (NE, H) f32

  char* ws = (char*)d_ws;
  f16* x_f16  = (f16*)(ws);                                   //  8 MB: [4096][1024]
  f16* wqkvT  = (f16*)(ws + 8388608);                         //  6 MB: [3072][1024]
  f16* wprojT = (f16*)(ws + 8388608 + 6291456);               //  2 MB: [1024][1024]
  f16* qkv    = (f16*)(ws + 8388608 + 6291456 + 2097152);     // 24 MB: [4096][3072]
  f16* attn_o = x_f16;  // reuse: x_f16 dead after QKV GEMM

  cvt_f2h_kernel<<<4096, 256, 0, stream>>>((const float4*)x_f32, (uint2*)x_f16, 1048576);
  transpose_cvt_kernel<<<dim3(48, 16), 256, 0, stream>>>(wqkv, wqkvT, 1024, 3072);
  transpose_cvt_kernel<<<dim3(16, 16), 256, 0, stream>>>(wproj, wprojT, 1024, 1024);
  gemm_f16_kernel<<<dim3(24, 32), 256, 0, stream>>>(x_f16, wqkvT, qkv, 4096, 3072, 1024, 0);
  attn_kernel<<<1024, 256, 0, stream>>>(qkv, gadj, etype, adjb, etab, attn_o);
  gemm_f16_kernel<<<dim3(8, 32), 256, 0, stream>>>(attn_o, wprojT, d_out, 4096, 1024, 1024, 1);
}

// Round 3
// 292.281 us; speedup vs baseline: 1.4519x; 1.4519x over previous
//
#include <hip/hip_runtime.h>
#include <stdint.h>

#define TT 2048
#define HH 16
#define LOG2E 1.44269504089f

typedef _Float16 f16;
typedef __attribute__((ext_vector_type(8))) _Float16 f16x8;
typedef __attribute__((ext_vector_type(4))) float f32x4;
typedef unsigned short ushort_t;

// async global->LDS, 16B per lane (GEMM only)
__device__ __forceinline__ void gl_lds16(const void* g, void* l){
  __builtin_amdgcn_global_load_lds(
      (__attribute__((address_space(1))) void*)(void*)g,
      (__attribute__((address_space(3))) void*)l, 16, 0, 0);
}

// barrier WITHOUT vmcnt drain: LDS ops done, but global loads stay in flight
__device__ __forceinline__ void lds_barrier(){
  __asm__ volatile("s_waitcnt lgkmcnt(0)\n\ts_barrier" ::: "memory");
}

// ---------------- convert x: f32 -> f16 ----------------
__global__ __launch_bounds__(256) void cvt_f2h_kernel(const float4* __restrict__ in,
                                                      uint2* __restrict__ out, int n4){
  int i = blockIdx.x * 256 + threadIdx.x;
  if (i >= n4) return;
  float4 v = in[i];
  union { f16 h[4]; uint2 u; } o;
  o.h[0] = (f16)v.x; o.h[1] = (f16)v.y; o.h[2] = (f16)v.z; o.h[3] = (f16)v.w;
  out[i] = o.u;
}

// ---------------- transpose+convert: f32 [R][C] -> f16 [C][R] ----------------
__global__ __launch_bounds__(256) void transpose_cvt_kernel(const float* __restrict__ in,
                                                            f16* __restrict__ out, int R, int C){
  __shared__ float tile[64][65];
  int c0 = blockIdx.x * 64, r0 = blockIdx.y * 64;
  int t = threadIdx.x;
  int row = t >> 2, cs = (t & 3) << 4;
  const float4* src = (const float4*)(in + (size_t)(r0 + row) * C + c0 + cs);
  float4 a = src[0], b = src[1], c = src[2], d = src[3];
  float* tr = &tile[row][cs];
  tr[0]=a.x; tr[1]=a.y; tr[2]=a.z;  tr[3]=a.w;
  tr[4]=b.x; tr[5]=b.y; tr[6]=b.z;  tr[7]=b.w;
  tr[8]=c.x; tr[9]=c.y; tr[10]=c.z; tr[11]=c.w;
  tr[12]=d.x;tr[13]=d.y;tr[14]=d.z; tr[15]=d.w;
  __syncthreads();
  f16 tmp[16];
  #pragma unroll
  for (int j = 0; j < 16; ++j) tmp[j] = (f16)tile[cs + j][row];
  f16* dst = out + (size_t)(c0 + row) * R + r0 + cs;
  *(uint4*)dst = *(uint4*)&tmp[0];
  *(uint4*)(dst + 8) = *(uint4*)&tmp[8];
}

// ---------------- GEMM: C[M][N] = A[M][K] @ Bt[N][K]^T ----------------
__global__ __launch_bounds__(256) void gemm_f16_kernel(const f16* __restrict__ A,
                                                       const f16* __restrict__ Bt,
                                                       void* __restrict__ Cout,
                                                       int M, int N, int K, int out_f32){
  __shared__ __align__(16) f16 As[128 * 32];
  __shared__ __align__(16) f16 Bs[128 * 32];
  int t = threadIdx.x;
  int w = t >> 6, lane = t & 63;
  int wm = (w >> 1) * 64, wn = (w & 1) * 64;
  int lrow = lane & 15, quad = lane >> 4;
  int bm = blockIdx.y, bn = blockIdx.x;

  f32x4 acc[4][4];
  for (int i = 0; i < 4; ++i)
    for (int j = 0; j < 4; ++j)
      for (int r = 0; r < 4; ++r) acc[i][j][r] = 0.f;

  const int nk = K >> 5;
  for (int kt = 0; kt < nk; ++kt){
    int k0 = kt << 5;
    __syncthreads();
    #pragma unroll
    for (int i = 0; i < 2; ++i){
      int c = (w << 7) + (i << 6) + lane;
      gl_lds16(A  + (size_t)((bm << 7) + (c >> 2)) * K + k0 + ((c & 3) << 3),
               As + ((w << 7) + (i << 6)) * 8);
      gl_lds16(Bt + (size_t)((bn << 7) + (c >> 2)) * K + k0 + ((c & 3) << 3),
               Bs + ((w << 7) + (i << 6)) * 8);
    }
    __syncthreads();
    f16x8 af[4], bfr[4];
    #pragma unroll
    for (int mi = 0; mi < 4; ++mi)
      af[mi] = *(const f16x8*)(As + (wm + mi * 16 + lrow) * 32 + quad * 8);
    #pragma unroll
    for (int ni = 0; ni < 4; ++ni)
      bfr[ni] = *(const f16x8*)(Bs + (wn + ni * 16 + lrow) * 32 + quad * 8);
    #pragma unroll
    for (int mi = 0; mi < 4; ++mi)
      #pragma unroll
      for (int ni = 0; ni < 4; ++ni)
        acc[mi][ni] = __builtin_amdgcn_mfma_f32_16x16x32_f16(af[mi], bfr[ni], acc[mi][ni], 0, 0, 0);
  }

  #pragma unroll
  for (int mi = 0; mi < 4; ++mi)
    #pragma unroll
    for (int ni = 0; ni < 4; ++ni)
      #pragma unroll
      for (int r = 0; r < 4; ++r){
        int row = (bm << 7) + wm + mi * 16 + quad * 4 + r;
        int col = (bn << 7) + wn + ni * 16 + lrow;
        float val = acc[mi][ni][r];
        if (out_f32) ((float*)Cout)[(size_t)row * N + col] = val;
        else         ((f16*)Cout)[(size_t)row * N + col] = (f16)val;
      }
}

// ---------------- fused causal graph attention, split-K chunks ----------------
// One block = (b, h, qt, chunk). CHUNK = 16 K-tiles (1024 keys).
// qt<16: single chunk, normalize + write directly. qt>=16: 2 chunks, write (O,m,l) partials.
__global__ __launch_bounds__(256, 4) void attn_kernel(const f16* __restrict__ qkv,
                                                      const float* __restrict__ gadj,
                                                      const int* __restrict__ etype,
                                                      const float* __restrict__ adj_bias,
                                                      const float* __restrict__ edge_table,
                                                      f16* __restrict__ attn_out,
                                                      f16* __restrict__ Opart,
                                                      float* __restrict__ MLpart){
  __shared__ __align__(16) f16 Ks[64 * 72];
  __shared__ __align__(16) f16 Vt[64 * 72];   // transposed [hd][key], xor-swizzled 16B blocks
  __shared__ __align__(16) f16 Ps[4][16 * 72];
  __shared__ float edge_lds[8 * 33];          // 8 replicas, stride 33 (bank spread)

  int bx = blockIdx.x;
  int h = bx & 15;
  int b = (bx >> 4) & 1;
  int j = bx >> 5;                    // [0,48), descending chunk size
  int qt, c0;
  if (j < 16){ qt = 16 + j; c0 = 0; }
  else { int p = (j - 16) >> 1;
         if (((j - 16) & 1) == 0){ qt = 15 - p; c0 = 0; }
         else                    { qt = 31 - p; c0 = 1; } }
  int ks = c0 << 4;
  int ke = min(qt, ks + 15);
  bool whole = (c0 == 0) && (qt <= 15);

  int t = threadIdx.x;
  int w = t >> 6, lane = t & 63;
  int lrow = lane & 15, quad = lane >> 4;

  if (t < 136){
    int cp = t / 17, e = t - cp * 17;
    edge_lds[cp * 33 + e] = edge_table[e * HH + h];
  }
  float adjb = adj_bias[h];
  int erep = (lane & 7) * 33;

  int q0 = qt * 64 + w * 16;
  const size_t qrow = ((size_t)b * TT + q0 + lrow) * 3072 + h * 64;
  f16x8 qf0 = *(const f16x8*)(qkv + qrow + quad * 8);
  f16x8 qf1 = *(const f16x8*)(qkv + qrow + 32 + quad * 8);

  f32x4 o[4];
  for (int i = 0; i < 4; ++i)
    for (int r = 0; r < 4; ++r) o[i][r] = 0.f;
  float mrun[4] = {-1e30f, -1e30f, -1e30f, -1e30f};
  float lrun[4] = {0.f, 0.f, 0.f, 0.f};

  // staging geometry (per thread, both halves): key = c>>3, hd0 = (c&7)*8
  const int keyA = t >> 3,        hdA = (t & 7) << 3;
  const int keyB = 32 + (t >> 3), hdB = hdA;
  const int sA = ((keyA >> 3) ^ (hdA >> 3)) & 7;  // keyA>>3 == 0, kept for clarity
  const int sB = ((keyB >> 3) ^ (hdB >> 3)) & 7;
  const f16* kbase = qkv + (size_t)b * TT * 3072 + 1024 + h * 64;
  const f16* vbase = qkv + (size_t)b * TT * 3072 + 2048 + h * 64;

  for (int kt2 = ks; kt2 <= ke; ++kt2){
    lds_barrier();   // prev-iter LDS reads done; global (bias) loads may remain in flight
    // ---- issue global loads: K, V, then bias (bias stays outstanding across barrier)
    uint4 kv0 = *(const uint4*)(kbase + (size_t)(kt2 * 64 + keyA) * 3072 + hdA);
    uint4 kv1 = *(const uint4*)(kbase + (size_t)(kt2 * 64 + keyB) * 3072 + hdB);
    uint4 vv0 = *(const uint4*)(vbase + (size_t)(kt2 * 64 + keyA) * 3072 + hdA);
    uint4 vv1 = *(const uint4*)(vbase + (size_t)(kt2 * 64 + keyB) * 3072 + hdB);

    int qgb = q0 + quad * 4;
    int kgb = kt2 * 64 + lrow;
    float gv[16]; int ev[16];
    #pragma unroll
    for (int nb = 0; nb < 4; ++nb){
      size_t idx0 = ((size_t)b * TT + qgb) * TT + kgb + nb * 16;
      #pragma unroll
      for (int r = 0; r < 4; ++r){
        size_t idx = idx0 + (size_t)r * TT;
        gv[nb * 4 + r] = gadj[idx];
        ev[nb * 4 + r] = etype[idx];
      }
    }

    // ---- LDS writes: K rows (b128), V transposed (scalar, conflict-free pattern)
    *(uint4*)(Ks + keyA * 72 + hdA) = kv0;
    *(uint4*)(Ks + keyB * 72 + hdB) = kv1;
    {
      union { uint4 u; f16 hh[8]; } ua, ub;
      ua.u = vv0; ub.u = vv1;
      #pragma unroll
      for (int jj = 0; jj < 8; ++jj){
        Vt[(hdA + jj) * 72 + (sA << 3) + (keyA & 7)] = ua.hh[jj];
        Vt[(hdB + jj) * 72 + (sB << 3) + (keyB & 7)] = ub.hh[jj];
      }
    }
    lds_barrier();

    // ---- S = Q K^T
    f32x4 sf[4];
    #pragma unroll
    for (int nb = 0; nb < 4; ++nb){
      f32x4 s = {0.f, 0.f, 0.f, 0.f};
      f16x8 kf0 = *(const f16x8*)(Ks + (nb * 16 + lrow) * 72 + quad * 8);
      f16x8 kf1 = *(const f16x8*)(Ks + (nb * 16 + lrow) * 72 + 32 + quad * 8);
      s = __builtin_amdgcn_mfma_f32_16x16x32_f16(qf0, kf0, s, 0, 0, 0);
      s = __builtin_amdgcn_mfma_f32_16x16x32_f16(qf1, kf1, s, 0, 0, 0);
      sf[nb] = s;
    }

    // ---- bias + causal mask (C-layout: row = quad*4+r, col = lrow)
    float sarr[4][4];
    bool diag = (kt2 == qt);
    #pragma unroll
    for (int nb = 0; nb < 4; ++nb){
      int kg = kgb + nb * 16;
      #pragma unroll
      for (int r = 0; r < 4; ++r){
        float v;
        if (diag && kg > qgb + r) v = -1e30f;
        else v = sf[nb][r] * 0.125f + adjb * gv[nb * 4 + r] + edge_lds[erep + ev[nb * 4 + r]];
        sarr[nb][r] = v;
      }
    }

    // ---- online softmax (rows across 16 lanes of a quad)
    float pv_[4][4];
    #pragma unroll
    for (int r = 0; r < 4; ++r){
      float mx = fmaxf(fmaxf(sarr[0][r], sarr[1][r]), fmaxf(sarr[2][r], sarr[3][r]));
      mx = fmaxf(mx, __shfl_xor(mx, 1));
      mx = fmaxf(mx, __shfl_xor(mx, 2));
      mx = fmaxf(mx, __shfl_xor(mx, 4));
      mx = fmaxf(mx, __shfl_xor(mx, 8));
      float mnew = fmaxf(mrun[r], mx);
      float alpha = exp2f((mrun[r] - mnew) * LOG2E);
      mrun[r] = mnew;
      float rs = 0.f;
      #pragma unroll
      for (int nb = 0; nb < 4; ++nb){
        float p = exp2f((sarr[nb][r] - mnew) * LOG2E);
        pv_[nb][r] = p; rs += p;
      }
      rs += __shfl_xor(rs, 1); rs += __shfl_xor(rs, 2);
      rs += __shfl_xor(rs, 4); rs += __shfl_xor(rs, 8);
      lrun[r] = lrun[r] * alpha + rs;
      #pragma unroll
      for (int nbh = 0; nbh < 4; ++nbh) o[nbh][r] *= alpha;
    }

    // ---- P: C-layout -> LDS (pitch 72) -> A-layout (wave-private)
    f16* Pw = &Ps[w][0];
    #pragma unroll
    for (int nb = 0; nb < 4; ++nb)
      #pragma unroll
      for (int r = 0; r < 4; ++r)
        Pw[(quad * 4 + r) * 72 + nb * 16 + lrow] = (f16)pv_[nb][r];
    __asm__ volatile("s_waitcnt lgkmcnt(0)" ::: "memory");

    // ---- O += P V  (Vt b128 fragments, swizzled)
    #pragma unroll
    for (int cc = 0; cc < 2; ++cc){
      f16x8 pf = *(const f16x8*)(Pw + lrow * 72 + cc * 32 + quad * 8);
      #pragma unroll
      for (int nbh = 0; nbh < 4; ++nbh){
        int hd = nbh * 16 + lrow;
        int sb = (hd >> 3) & 7;
        f16x8 vf = *(const f16x8*)(Vt + hd * 72 + (((cc * 4 + quad) ^ sb) << 3));
        o[nbh] = __builtin_amdgcn_mfma_f32_16x16x32_f16(pf, vf, o[nbh], 0, 0, 0);
      }
    }
  }

  if (whole){
    float inv[4];
    #pragma unroll
    for (int r = 0; r < 4; ++r) inv[r] = 1.0f / lrun[r];
    #pragma unroll
    for (int nbh = 0; nbh < 4; ++nbh)
      #pragma unroll
      for (int r = 0; r < 4; ++r){
        int qg = q0 + quad * 4 + r;
        int col = h * 64 + nbh * 16 + lrow;
        attn_out[((size_t)b * TT + qg) * 1024 + col] = (f16)(o[nbh][r] * inv[r]);
      }
  } else {
    int slot = (((b * 16 + h) * 16) + (qt - 16)) * 2 + c0;
    f16* Ob = Opart + (size_t)slot * 4096;
    #pragma unroll
    for (int nbh = 0; nbh < 4; ++nbh)
      #pragma unroll
      for (int r = 0; r < 4; ++r)
        Ob[(w * 16 + quad * 4 + r) * 64 + nbh * 16 + lrow] = (f16)o[nbh][r];
    if (lrow == 0){
      #pragma unroll
      for (int r = 0; r < 4; ++r){
        int qq = w * 16 + quad * 4 + r;
        MLpart[(size_t)slot * 128 + qq] = mrun[r];
        MLpart[(size_t)slot * 128 + 64 + qq] = lrun[r];
      }
    }
  }
}

// ---------------- combine partials for qt>=16 ----------------
__global__ __launch_bounds__(256) void combine_kernel(const f16* __restrict__ Opart,
                                                      const float* __restrict__ ML,
                                                      f16* __restrict__ attn_out){
  int bx = blockIdx.x;           // (b*16+h)*16 + (qt-16), 512 blocks
  int t = threadIdx.x;
  int q = t >> 2;
  int hd0 = (t & 3) << 4;
  int slot0 = bx * 2;
  float m0 = ML[(size_t)slot0 * 128 + q],       l0 = ML[(size_t)slot0 * 128 + 64 + q];
  float m1 = ML[(size_t)(slot0 + 1) * 128 + q], l1 = ML[(size_t)(slot0 + 1) * 128 + 64 + q];
  float M = fmaxf(m0, m1);
  float w0 = exp2f((m0 - M) * LOG2E), w1 = exp2f((m1 - M) * LOG2E);
  float invL = 1.0f / (l0 * w0 + l1 * w1);

  const f16* O0 = Opart + (size_t)slot0 * 4096 + q * 64 + hd0;
  const f16* O1 = O0 + 4096;
  f16x8 a0 = *(const f16x8*)O0,   a1 = *(const f16x8*)(O0 + 8);
  f16x8 b0 = *(const f16x8*)O1,   b1 = *(const f16x8*)(O1 + 8);
  f16 outv[16];
  #pragma unroll
  for (int i = 0; i < 8; ++i){
    outv[i]     = (f16)(((float)a0[i] * w0 + (float)b0[i] * w1) * invL);
    outv[i + 8] = (f16)(((float)a1[i] * w0 + (float)b1[i] * w1) * invL);
  }
  int qt = (bx & 15) + 16, h = (bx >> 4) & 15, b = bx >> 8;
  int qg = qt * 64 + q;
  f16* dst = attn_out + ((size_t)b * TT + qg) * 1024 + h * 64 + hd0;
  *(uint4*)dst = *(uint4*)&outv[0];
  *(uint4*)(dst + 8) = *(uint4*)&outv[8];
}

extern "C" void kernel_launch(void* const* d_in, const int* in_sizes, int n_in,
                              void* d_out, int out_size, void* d_ws, size_t ws_size,
                              hipStream_t stream){
  (void)in_sizes; (void)n_in; (void)out_size; (void)ws_size;
  const float* x_f32  = (const float*)d_in[0];
  const float* gadj   = (const float*)d_in[1];
  const int*   etype  = (const int*)d_in[2];
  const float* wqkv   = (const float*)d_in[3];
  const float* wproj  = (const float*)d_in[4];
  const float* adjb   = (const float*)d_in[5];
  const float* etab   = (const float*)d_in[6];

  char* ws = (char*)d_ws;
  f16*   x_f16  = (f16*)(ws);                               //  8 MB
  f16*   wqkvT  = (f16*)(ws + (8u << 20));                  //  6 MB
  f16*   wprojT = (f16*)(ws + (14u << 20));                 //  2 MB
  f16*   qkv    = (f16*)(ws + (16u << 20));                 // 24 MB
  f16*   Opart  = (f16*)(ws + (40u << 20));                 //  8 MB (1024 slots x 4096 f16)
  float* MLpart = (float*)(ws + (48u << 20));               //  0.5 MB
  f16*   attn_o = x_f16;  // reuse

  cvt_f2h_kernel<<<4096, 256, 0, stream>>>((const float4*)x_f32, (uint2*)x_f16, 1048576);
  transpose_cvt_kernel<<<dim3(48, 16), 256, 0, stream>>>(wqkv, wqkvT, 1024, 3072);
  transpose_cvt_kernel<<<dim3(16, 16), 256, 0, stream>>>(wproj, wprojT, 1024, 1024);
  gemm_f16_kernel<<<dim3(24, 32), 256, 0, stream>>>(x_f16, wqkvT, qkv, 4096, 3072, 1024, 0);
  attn_kernel<<<1536, 256, 0, stream>>>(qkv, gadj, etype, adjb, etab, attn_o, Opart, MLpart);
  combine_kernel<<<512, 256, 0, stream>>>(Opart, MLpart, attn_o);
  gemm_f16_kernel<<<dim3(8, 32), 256, 0, stream>>>(attn_o, wprojT, d_out, 4096, 1024, 1024, 1);
}